// Round 3
// baseline (898.912 us; speedup 1.0000x reference)
//
#include <hip/hip_runtime.h>

typedef unsigned short u16;
typedef _Float16 f16x8 __attribute__((ext_vector_type(8)));
typedef float f32x4 __attribute__((ext_vector_type(4)));
typedef u16 u16x8 __attribute__((ext_vector_type(8)));

#define MINF (-0x1.fffffep+127f)
#define SCALE 0.08838834764831845f

__device__ __forceinline__ u16 f2h(float f) {
    _Float16 h = (_Float16)f;
    return __builtin_bit_cast(u16, h);
}
__device__ __forceinline__ float h2f(u16 u) {
    _Float16 h = __builtin_bit_cast(_Float16, u);
    return (float)h;
}

typedef const __attribute__((address_space(1))) void* gptr_t;
typedef __attribute__((address_space(3))) void* sptr_t;
#define GLDS16(g, l) __builtin_amdgcn_global_load_lds((gptr_t)(const void*)(g), (sptr_t)(void*)(l), 16, 0, 0)

// ---------------- f32 -> f16 conversion, 8 elem/thread (n must be divisible by 2048) ----------------
__global__ void convk8(const float* __restrict__ in, u16* __restrict__ out, int n) {
    int i = (blockIdx.x * 256 + threadIdx.x) * 8;
    if (i >= n) return;
    f32x4 a = *(const f32x4*)&in[i];
    f32x4 b = *(const f32x4*)&in[i + 4];
    u16x8 r;
#pragma unroll
    for (int j = 0; j < 4; ++j) { r[j] = f2h(a[j]); r[j + 4] = f2h(b[j]); }
    *(u16x8*)&out[i] = r;
}

// ---------------- GEMM C = A * Bw^T  (A: MxK row-major f16, Bw: NxK row-major f16) ----------------
// EPI=0: write f32 C (N param). EPI=1: QKV scatter epilogue (N=4096).
template <int EPI>
__global__ __launch_bounds__(256) void gemm_bt(
    const u16* __restrict__ A, const u16* __restrict__ Bw, float* __restrict__ Cf,
    u16* __restrict__ qo, u16* __restrict__ ko, u16* __restrict__ vto, int N, int K) {
    __shared__ alignas(16) u16 As[128 * 32];
    __shared__ alignas(16) u16 Bs[128 * 32];
    int tid = threadIdx.x;
    int wid = tid >> 6, lane = tid & 63;
    int l16 = lane & 15, lhi = lane >> 4;
    int bm = blockIdx.y * 128, bn = blockIdx.x * 128;
    int wr = (wid >> 1) * 64, wc = (wid & 1) * 64;
    int srow = lane >> 2, sseg = lane & 3;
    f32x4 acc[4][4] = {};
    for (int kt = 0; kt < K; kt += 32) {
        __syncthreads();
#pragma unroll
        for (int i = 0; i < 2; ++i) {
            const u16* ga = A + (size_t)(bm + i * 64 + wid * 16 + srow) * K + kt + sseg * 8;
            GLDS16(ga, &As[(i * 64 + wid * 16) * 32]);
            const u16* gb = Bw + (size_t)(bn + i * 64 + wid * 16 + srow) * K + kt + sseg * 8;
            GLDS16(gb, &Bs[(i * 64 + wid * 16) * 32]);
        }
        __syncthreads();
        f16x8 af[4], bf[4];
#pragma unroll
        for (int mi = 0; mi < 4; ++mi) af[mi] = *(const f16x8*)&As[(wr + mi * 16 + l16) * 32 + lhi * 8];
#pragma unroll
        for (int ni = 0; ni < 4; ++ni) bf[ni] = *(const f16x8*)&Bs[(wc + ni * 16 + l16) * 32 + lhi * 8];
#pragma unroll
        for (int mi = 0; mi < 4; ++mi)
#pragma unroll
            for (int ni = 0; ni < 4; ++ni)
                acc[mi][ni] = __builtin_amdgcn_mfma_f32_16x16x32_f16(af[mi], bf[ni], acc[mi][ni], 0, 0, 0);
    }
#pragma unroll
    for (int mi = 0; mi < 4; ++mi) {
#pragma unroll
        for (int ni = 0; ni < 4; ++ni) {
#pragma unroll
            for (int j = 0; j < 4; ++j) {
                int r = bm + wr + mi * 16 + lhi * 4 + j;
                int c = bn + wc + ni * 16 + l16;
                float val = acc[mi][ni][j];
                if (EPI == 0) {
                    Cf[(size_t)r * N + c] = val;
                } else {
                    u16 hv = f2h(val);
                    int b = r >> 11, s = r & 2047;
                    if (c < 2048) {
                        int hh = c >> 7, d = c & 127;
                        qo[(((size_t)(b * 16 + hh)) * 2048 + s) * 128 + d] = hv;
                    } else if (c < 3072) {
                        int hh = (c - 2048) >> 7, d = c & 127;
                        ko[(((size_t)(b * 8 + hh)) * 2048 + s) * 128 + d] = hv;
                    } else {
                        int hh = (c - 3072) >> 7, d = c & 127;
                        vto[(((size_t)(b * 8 + hh)) * 128 + d) * 2048 + s] = hv;
                    }
                }
            }
        }
    }
}

// ---------------- RoPE (in-place on f16 (B,nh,S,128)) ----------------
__global__ void rope_kernel(u16* __restrict__ t, const float* __restrict__ cosv,
                            const float* __restrict__ sinv, int nheads) {
    int i = blockIdx.x * 256 + threadIdx.x;
    int total = 2 * nheads * 2048 * 64;
    if (i >= total) return;
    int d = i & 63;
    int s = (i >> 6) & 2047;
    int bh = i >> 17;
    int b = bh / nheads;
    size_t base = ((size_t)bh * 2048 + s) * 128;
    size_t cb = ((size_t)b * 2048 + s) * 128;
    float x1 = h2f(t[base + d]), x2 = h2f(t[base + d + 64]);
    float c1 = cosv[cb + d], s1 = sinv[cb + d];
    float c2 = cosv[cb + d + 64], s2 = sinv[cb + d + 64];
    t[base + d] = f2h(x1 * c1 - x2 * s1);
    t[base + d + 64] = f2h(x2 * c2 + x1 * s2);
}

// ---------------- Wdtv = Wdt (16x1024) @ Wv (1024x2048), f32 ----------------
__global__ void wdtv_kernel(const float* __restrict__ Wdt, const float* __restrict__ Wv,
                            float* __restrict__ out) {
    __shared__ float wdt_s[16 * 1024];
    int t = threadIdx.x;  // 64 threads
    for (int i = t; i < 16 * 1024; i += 64) wdt_s[i] = Wdt[i];
    __syncthreads();
    int c = blockIdx.x * 64 + t;
    float acc[16];
#pragma unroll
    for (int h = 0; h < 16; ++h) acc[h] = 0.f;
    for (int f = 0; f < 1024; ++f) {
        float wv = Wv[(size_t)f * 2048 + c];
#pragma unroll
        for (int h = 0; h < 16; ++h) acc[h] += wdt_s[h * 1024 + f] * wv;
    }
#pragma unroll
    for (int h = 0; h < 16; ++h) out[h * 2048 + c] = acc[h];
}

// ---------------- dt = x @ Wdtv^T ; dyn = exp(A*softplus(dt)), layout (B,H,S) f32 ----------------
__global__ void dt_dyn_kernel(const float* __restrict__ x, const float* __restrict__ Wdtv,
                              const float* __restrict__ Av, float* __restrict__ dyn) {
    __shared__ float xrow[2048];
    __shared__ float red[256];
    int bs = blockIdx.x;
    int t = threadIdx.x;
    for (int i = t; i < 2048; i += 256) xrow[i] = x[(size_t)bs * 2048 + i];
    __syncthreads();
    int h = t & 15, chunk = t >> 4;
    float p = 0.f;
    const float* wrow = Wdtv + h * 2048 + chunk * 128;
    const float* xr = xrow + chunk * 128;
    for (int f = 0; f < 128; ++f) p += xr[f] * wrow[f];
    red[t] = p;
    __syncthreads();
    if (t < 16) {
        float dt = 0.f;
        for (int c = 0; c < 16; ++c) dt += red[c * 16 + t];
        float sp = fmaxf(dt, 0.f) + log1pf(expf(-fabsf(dt)));
        int b = bs >> 11, s = bs & 2047;
        dyn[((size_t)(b * 16 + t)) * 2048 + s] = expf(Av[t] * sp);
    }
}

// ---------------- kth (1024th smallest of 2048) + mask values ----------------
__global__ void kth_mask_kernel(const float* __restrict__ dyn, float* __restrict__ mval) {
    __shared__ float sv[2048];
    int bh = blockIdx.x, t = threadIdx.x;  // 1024 threads
    const float* row = dyn + (size_t)bh * 2048;
    sv[t] = row[t];
    sv[t + 1024] = row[t + 1024];
    __syncthreads();
    for (int k = 2; k <= 2048; k <<= 1) {
        for (int j = k >> 1; j > 0; j >>= 1) {
#pragma unroll 1
            for (int base = 0; base < 2048; base += 1024) {
                int i = base + t;
                int ixj = i ^ j;
                if (ixj > i) {
                    float a = sv[i], b = sv[ixj];
                    bool up = ((i & k) == 0);
                    if ((a > b) == up) { sv[i] = b; sv[ixj] = a; }
                }
            }
            __syncthreads();
        }
    }
    float kth = sv[1023];
    float v0 = row[t];
    float v1 = row[t + 1024];
    mval[(size_t)bh * 2048 + t] = v0 < kth ? MINF : v0;
    mval[(size_t)bh * 2048 + t + 1024] = v1 < kth ? MINF : v1;
}

// ---------------- flash attention, causal + dynamic mask, GQA ----------------
// q: (B,16,S,128) f16; k: (B,8,S,128) f16; vt: (B,8,128,S) f16; mval: (B,16,S) f32
// out: attn_out (B,S,16*128) f16
__global__ __launch_bounds__(256) void attn_kernel(
    const u16* __restrict__ qb, const u16* __restrict__ kb, const u16* __restrict__ vtb,
    const float* __restrict__ mv, u16* __restrict__ ao) {
    int bh = blockIdx.y, qt = blockIdx.x;
    int b = bh >> 4, h = bh & 15, kvh = h >> 1;
    int wid = threadIdx.x >> 6, lane = threadIdx.x & 63;
    int l16 = lane & 15, lhi = lane >> 4;
    int q0 = qt * 64 + wid * 16;
    const u16* qbase = qb + (((size_t)bh * 2048) + q0) * 128;
    const u16* kbase = kb + ((size_t)(b * 8 + kvh) * 2048) * 128;
    const u16* vtbase = vtb + ((size_t)(b * 8 + kvh) * 128) * 2048;
    const float* mvb = mv + (size_t)bh * 2048;
    __shared__ alignas(16) u16 plds[4][16 * 64];
    u16* pw = plds[wid];
    f16x8 qf[4];
#pragma unroll
    for (int kc = 0; kc < 4; ++kc) qf[kc] = *(const f16x8*)&qbase[l16 * 128 + kc * 32 + lhi * 8];
    float m[4], lsum[4];
#pragma unroll
    for (int j = 0; j < 4; ++j) { m[j] = -INFINITY; lsum[j] = 0.f; }
    f32x4 accO[8] = {};
    for (int kt = 0; kt < 32; ++kt) {
        int kvb = kt * 64;
        if (kvb >= q0 + 16) {
            // past causal frontier for this wave: continue only for degenerate rows
            bool deg = (m[0] == MINF) | (m[1] == MINF) | (m[2] == MINF) | (m[3] == MINF);
            if (!__any(deg)) break;
        }
        f32x4 sc[4] = {};
#pragma unroll
        for (int ni = 0; ni < 4; ++ni) {
            const u16* kr = &kbase[(size_t)(kvb + ni * 16 + l16) * 128 + lhi * 8];
#pragma unroll
            for (int kc = 0; kc < 4; ++kc) {
                f16x8 kf = *(const f16x8*)&kr[kc * 32];
                sc[ni] = __builtin_amdgcn_mfma_f32_16x16x32_f16(qf[kc], kf, sc[ni], 0, 0, 0);
            }
        }
        float rmax[4] = {-INFINITY, -INFINITY, -INFINITY, -INFINITY};
#pragma unroll
        for (int ni = 0; ni < 4; ++ni) {
            int key = kvb + ni * 16 + l16;
            float mk = mvb[key];
#pragma unroll
            for (int j = 0; j < 4; ++j) {
                int qrow = q0 + lhi * 4 + j;
                // exact reference arithmetic: mask = dynmask + causalMIN (f32, may overflow to -inf),
                // then score = qk*scale + mask (MIN absorbs qk*scale).
                float sval = sc[ni][j] * SCALE + (mk + (key > qrow ? MINF : 0.f));
                sc[ni][j] = sval;
                rmax[j] = fmaxf(rmax[j], sval);
            }
        }
#pragma unroll
        for (int j = 0; j < 4; ++j) {
#pragma unroll
            for (int off = 1; off < 16; off <<= 1) rmax[j] = fmaxf(rmax[j], __shfl_xor(rmax[j], off));
        }
        float r[4], psum[4];
#pragma unroll
        for (int j = 0; j < 4; ++j) {
            float mn = fmaxf(m[j], rmax[j]);
            r[j] = expf(m[j] - mn);
            m[j] = mn;
            psum[j] = 0.f;
        }
#pragma unroll
        for (int ni = 0; ni < 4; ++ni) {
#pragma unroll
            for (int j = 0; j < 4; ++j) {
                float p = expf(sc[ni][j] - m[j]);
                psum[j] += p;
                pw[(lhi * 4 + j) * 64 + ni * 16 + l16] = f2h(p);
            }
        }
#pragma unroll
        for (int j = 0; j < 4; ++j) {
#pragma unroll
            for (int off = 1; off < 16; off <<= 1) psum[j] += __shfl_xor(psum[j], off);
            lsum[j] = lsum[j] * r[j] + psum[j];
        }
#pragma unroll
        for (int db = 0; db < 8; ++db) {
#pragma unroll
            for (int j = 0; j < 4; ++j) accO[db][j] *= r[j];
        }
#pragma unroll
        for (int kc2 = 0; kc2 < 2; ++kc2) {
            f16x8 pa = *(const f16x8*)&pw[l16 * 64 + kc2 * 32 + lhi * 8];
#pragma unroll
            for (int db = 0; db < 8; ++db) {
                f16x8 vf = *(const f16x8*)&vtbase[(size_t)(db * 16 + l16) * 2048 + kvb + kc2 * 32 + lhi * 8];
                accO[db] = __builtin_amdgcn_mfma_f32_16x16x32_f16(pa, vf, accO[db], 0, 0, 0);
            }
        }
    }
#pragma unroll
    for (int db = 0; db < 8; ++db) {
#pragma unroll
        for (int j = 0; j < 4; ++j) {
            int qrow = q0 + lhi * 4 + j;
            int d = db * 16 + l16;
            float o = accO[db][j] / lsum[j];
            ao[((size_t)(b * 2048) + qrow) * 2048 + h * 128 + d] = f2h(o);
        }
    }
}

extern "C" void kernel_launch(void* const* d_in, const int* in_sizes, int n_in,
                              void* d_out, int out_size, void* d_ws, size_t ws_size,
                              hipStream_t stream) {
    const float* x = (const float*)d_in[0];
    const float* cosv = (const float*)d_in[1];
    const float* sinv = (const float*)d_in[2];
    // d_in[3] = attention_mask (deterministic causal MIN mask) -- synthesized in-kernel
    const float* Wq = (const float*)d_in[4];
    const float* Wk = (const float*)d_in[5];
    const float* Wv = (const float*)d_in[6];
    const float* Av = (const float*)d_in[7];
    const float* Wdt = (const float*)d_in[8];
    const float* Wo = (const float*)d_in[9];

    char* ws = (char*)d_ws;
    u16* qb = (u16*)(ws);                    // 16,777,216 B  (B,16,S,128) f16
    u16* kb = (u16*)(ws + 16777216);         //  8,388,608 B  (B,8,S,128) f16
    u16* vtb = (u16*)(ws + 25165824);        //  8,388,608 B  (B,8,128,S) f16
    float* dyn = (float*)(ws + 33554432);    //    262,144 B  (B,16,S) f32
    float* mval = (float*)(ws + 33816576);   //    262,144 B  (B,16,S) f32
    float* wdtv = (float*)(ws + 34078720);   //    131,072 B  (16,2048) f32
    u16* xbf = (u16*)(ws + 34209792);        // 16,777,216 B  x_f16, later attn_out
    u16* wbf = (u16*)(ws + 50987008);        // 16,777,216 B  Wqkv_f16, later Wo_f16

    // 1. conversions to f16 (8 elem/thread)
    convk8<<<8388608 / 2048, 256, 0, stream>>>(x, xbf, 8388608);
    convk8<<<4194304 / 2048, 256, 0, stream>>>(Wq, wbf, 4194304);
    convk8<<<2097152 / 2048, 256, 0, stream>>>(Wk, wbf + 4194304, 2097152);
    convk8<<<2097152 / 2048, 256, 0, stream>>>(Wv, wbf + 6291456, 2097152);

    // 2. fused QKV GEMM, scatter epilogue (q/k per-head layout, v transposed)
    dim3 g1(32, 32);
    gemm_bt<1><<<g1, 256, 0, stream>>>(xbf, wbf, nullptr, qb, kb, vtb, 4096, 2048);

    // 3. RoPE in-place on q and k
    rope_kernel<<<16384, 256, 0, stream>>>(qb, cosv, sinv, 16);
    rope_kernel<<<8192, 256, 0, stream>>>(kb, cosv, sinv, 8);

    // 4. dynamic mask: Wdtv = Wdt@Wv (f32), dt = x@Wdtv^T (f32, matches ref to ~1e-5), top-k
    wdtv_kernel<<<32, 64, 0, stream>>>(Wdt, Wv, wdtv);
    dt_dyn_kernel<<<4096, 256, 0, stream>>>(x, wdtv, Av, dyn);
    kth_mask_kernel<<<32, 1024, 0, stream>>>(dyn, mval);

    // 5. Wo -> f16 (reuses wbf; QKV GEMM is done by stream order)
    convk8<<<4194304 / 2048, 256, 0, stream>>>(Wo, wbf, 4194304);

    // 6. attention (writes attn_out into xbf)
    dim3 g2(32, 32);
    attn_kernel<<<g2, 256, 0, stream>>>(qb, kb, vtb, mval, xbf);

    // 7. output projection -> f32 d_out
    dim3 g3(16, 32);
    gemm_bt<0><<<g3, 256, 0, stream>>>(xbf, wbf, (float*)d_out, nullptr, nullptr, nullptr, 2048, 2048);
}

// Round 4
// 766.131 us; speedup vs baseline: 1.1733x; 1.1733x over previous
//
#include <hip/hip_runtime.h>

typedef unsigned short u16;
typedef _Float16 f16x8 __attribute__((ext_vector_type(8)));
typedef float f32x4 __attribute__((ext_vector_type(4)));
typedef u16 u16x8 __attribute__((ext_vector_type(8)));

#define MINF (-0x1.fffffep+127f)
#define SCALE 0.08838834764831845f

__device__ __forceinline__ u16 f2h(float f) {
    _Float16 h = (_Float16)f;
    return __builtin_bit_cast(u16, h);
}
__device__ __forceinline__ float h2f(u16 u) {
    _Float16 h = __builtin_bit_cast(_Float16, u);
    return (float)h;
}

typedef const __attribute__((address_space(1))) void* gptr_t;
typedef __attribute__((address_space(3))) void* sptr_t;
#define GLDS16(g, l) __builtin_amdgcn_global_load_lds((gptr_t)(const void*)(g), (sptr_t)(void*)(l), 16, 0, 0)

// ---------------- f32 -> f16 conversion, 8 elem/thread (n must be divisible by 2048) ----------------
__global__ void convk8(const float* __restrict__ in, u16* __restrict__ out, int n) {
    int i = (blockIdx.x * 256 + threadIdx.x) * 8;
    if (i >= n) return;
    f32x4 a = *(const f32x4*)&in[i];
    f32x4 b = *(const f32x4*)&in[i + 4];
    u16x8 r;
#pragma unroll
    for (int j = 0; j < 4; ++j) { r[j] = f2h(a[j]); r[j + 4] = f2h(b[j]); }
    *(u16x8*)&out[i] = r;
}

// ---------------- GEMM C = A * Bw^T  (A: MxK row-major f16, Bw: NxK row-major f16) ----------------
// EPI=0: write f32 C (N param). EPI=1: QKV scatter epilogue (N=4096).
template <int EPI>
__global__ __launch_bounds__(256) void gemm_bt(
    const u16* __restrict__ A, const u16* __restrict__ Bw, float* __restrict__ Cf,
    u16* __restrict__ qo, u16* __restrict__ ko, u16* __restrict__ vto, int N, int K) {
    __shared__ alignas(16) u16 As[128 * 32];
    __shared__ alignas(16) u16 Bs[128 * 32];
    int tid = threadIdx.x;
    int wid = tid >> 6, lane = tid & 63;
    int l16 = lane & 15, lhi = lane >> 4;
    int bm = blockIdx.y * 128, bn = blockIdx.x * 128;
    int wr = (wid >> 1) * 64, wc = (wid & 1) * 64;
    int srow = lane >> 2, sseg = lane & 3;
    f32x4 acc[4][4] = {};
    for (int kt = 0; kt < K; kt += 32) {
        __syncthreads();
#pragma unroll
        for (int i = 0; i < 2; ++i) {
            const u16* ga = A + (size_t)(bm + i * 64 + wid * 16 + srow) * K + kt + sseg * 8;
            GLDS16(ga, &As[(i * 64 + wid * 16) * 32]);
            const u16* gb = Bw + (size_t)(bn + i * 64 + wid * 16 + srow) * K + kt + sseg * 8;
            GLDS16(gb, &Bs[(i * 64 + wid * 16) * 32]);
        }
        __syncthreads();
        f16x8 af[4], bf[4];
#pragma unroll
        for (int mi = 0; mi < 4; ++mi) af[mi] = *(const f16x8*)&As[(wr + mi * 16 + l16) * 32 + lhi * 8];
#pragma unroll
        for (int ni = 0; ni < 4; ++ni) bf[ni] = *(const f16x8*)&Bs[(wc + ni * 16 + l16) * 32 + lhi * 8];
#pragma unroll
        for (int mi = 0; mi < 4; ++mi)
#pragma unroll
            for (int ni = 0; ni < 4; ++ni)
                acc[mi][ni] = __builtin_amdgcn_mfma_f32_16x16x32_f16(af[mi], bf[ni], acc[mi][ni], 0, 0, 0);
    }
#pragma unroll
    for (int mi = 0; mi < 4; ++mi) {
#pragma unroll
        for (int ni = 0; ni < 4; ++ni) {
#pragma unroll
            for (int j = 0; j < 4; ++j) {
                int r = bm + wr + mi * 16 + lhi * 4 + j;
                int c = bn + wc + ni * 16 + l16;
                float val = acc[mi][ni][j];
                if (EPI == 0) {
                    Cf[(size_t)r * N + c] = val;
                } else {
                    u16 hv = f2h(val);
                    int b = r >> 11, s = r & 2047;
                    if (c < 2048) {
                        int hh = c >> 7, d = c & 127;
                        qo[(((size_t)(b * 16 + hh)) * 2048 + s) * 128 + d] = hv;
                    } else if (c < 3072) {
                        int hh = (c - 2048) >> 7, d = c & 127;
                        ko[(((size_t)(b * 8 + hh)) * 2048 + s) * 128 + d] = hv;
                    } else {
                        int hh = (c - 3072) >> 7, d = c & 127;
                        vto[(((size_t)(b * 8 + hh)) * 128 + d) * 2048 + s] = hv;
                    }
                }
            }
        }
    }
}

// ---------------- RoPE (in-place on f16 (B,nh,S,128)) ----------------
__global__ void rope_kernel(u16* __restrict__ t, const float* __restrict__ cosv,
                            const float* __restrict__ sinv, int nheads) {
    int i = blockIdx.x * 256 + threadIdx.x;
    int total = 2 * nheads * 2048 * 64;
    if (i >= total) return;
    int d = i & 63;
    int s = (i >> 6) & 2047;
    int bh = i >> 17;
    int b = bh / nheads;
    size_t base = ((size_t)bh * 2048 + s) * 128;
    size_t cb = ((size_t)b * 2048 + s) * 128;
    float x1 = h2f(t[base + d]), x2 = h2f(t[base + d + 64]);
    float c1 = cosv[cb + d], s1 = sinv[cb + d];
    float c2 = cosv[cb + d + 64], s2 = sinv[cb + d + 64];
    t[base + d] = f2h(x1 * c1 - x2 * s1);
    t[base + d + 64] = f2h(x2 * c2 + x1 * s2);
}

// ---------------- Wdtv = Wdt (16x1024) @ Wv (1024x2048), f32 ----------------
__global__ void wdtv_kernel(const float* __restrict__ Wdt, const float* __restrict__ Wv,
                            float* __restrict__ out) {
    __shared__ float wdt_s[16 * 1024];
    int t = threadIdx.x;  // 64 threads
    for (int i = t; i < 16 * 1024; i += 64) wdt_s[i] = Wdt[i];
    __syncthreads();
    int c = blockIdx.x * 64 + t;
    float acc[16];
#pragma unroll
    for (int h = 0; h < 16; ++h) acc[h] = 0.f;
    for (int f = 0; f < 1024; ++f) {
        float wv = Wv[(size_t)f * 2048 + c];
#pragma unroll
        for (int h = 0; h < 16; ++h) acc[h] += wdt_s[h * 1024 + f] * wv;
    }
#pragma unroll
    for (int h = 0; h < 16; ++h) out[h * 2048 + c] = acc[h];
}

// ---------------- dt = x @ Wdtv^T ; dyn = exp(A*softplus(dt)), layout (B,H,S) f32 ----------------
__global__ void dt_dyn_kernel(const float* __restrict__ x, const float* __restrict__ Wdtv,
                              const float* __restrict__ Av, float* __restrict__ dyn) {
    __shared__ float xrow[2048];
    __shared__ float red[256];
    int bs = blockIdx.x;
    int t = threadIdx.x;
    for (int i = t; i < 2048; i += 256) xrow[i] = x[(size_t)bs * 2048 + i];
    __syncthreads();
    int h = t & 15, chunk = t >> 4;
    float p = 0.f;
    const float* wrow = Wdtv + h * 2048 + chunk * 128;
    const float* xr = xrow + chunk * 128;
    for (int f = 0; f < 128; ++f) p += xr[f] * wrow[f];
    red[t] = p;
    __syncthreads();
    if (t < 16) {
        float dt = 0.f;
        for (int c = 0; c < 16; ++c) dt += red[c * 16 + t];
        float sp = fmaxf(dt, 0.f) + log1pf(expf(-fabsf(dt)));
        int b = bs >> 11, s = bs & 2047;
        dyn[((size_t)(b * 16 + t)) * 2048 + s] = expf(Av[t] * sp);
    }
}

// ---------------- kth (1024th smallest of 2048) + mask values ----------------
__global__ void kth_mask_kernel(const float* __restrict__ dyn, float* __restrict__ mval) {
    __shared__ float sv[2048];
    int bh = blockIdx.x, t = threadIdx.x;  // 1024 threads
    const float* row = dyn + (size_t)bh * 2048;
    sv[t] = row[t];
    sv[t + 1024] = row[t + 1024];
    __syncthreads();
    for (int k = 2; k <= 2048; k <<= 1) {
        for (int j = k >> 1; j > 0; j >>= 1) {
#pragma unroll 1
            for (int base = 0; base < 2048; base += 1024) {
                int i = base + t;
                int ixj = i ^ j;
                if (ixj > i) {
                    float a = sv[i], b = sv[ixj];
                    bool up = ((i & k) == 0);
                    if ((a > b) == up) { sv[i] = b; sv[ixj] = a; }
                }
            }
            __syncthreads();
        }
    }
    float kth = sv[1023];
    float v0 = row[t];
    float v1 = row[t + 1024];
    mval[(size_t)bh * 2048 + t] = v0 < kth ? MINF : v0;
    mval[(size_t)bh * 2048 + t + 1024] = v1 < kth ? MINF : v1;
}

// ---------------- flash attention, causal + dynamic mask, GQA ----------------
// q: (B,16,S,128) f16; k: (B,8,S,128) f16; vt: (B,8,128,S) f16; mval: (B,16,S) f32
// out: attn_out (B,S,16*128) f16
// Block = 128 threads (2 waves), 32 q-rows; grid (32 bh, 64 qtiles), longest-first.
__global__ __launch_bounds__(128) void attn_kernel(
    const u16* __restrict__ qb, const u16* __restrict__ kb, const u16* __restrict__ vtb,
    const float* __restrict__ mv, u16* __restrict__ ao) {
    int bh = blockIdx.x;
    int qt = 63 - blockIdx.y;  // longest-first dispatch to fight triangular drain
    int b = bh >> 4, h = bh & 15, kvh = h >> 1;
    int wid = threadIdx.x >> 6, lane = threadIdx.x & 63;
    int l16 = lane & 15, lhi = lane >> 4;
    int q0 = qt * 32 + wid * 16;
    const u16* qbase = qb + (((size_t)bh * 2048) + q0) * 128;
    const u16* kbase = kb + ((size_t)(b * 8 + kvh) * 2048) * 128;
    const u16* vtbase = vtb + ((size_t)(b * 8 + kvh) * 128) * 2048;
    const float* mvb = mv + (size_t)bh * 2048;
    __shared__ alignas(16) u16 plds[2][16 * 64];
    u16* pw = plds[wid];
    f16x8 qf[4];
#pragma unroll
    for (int kc = 0; kc < 4; ++kc) qf[kc] = *(const f16x8*)&qbase[l16 * 128 + kc * 32 + lhi * 8];
    float m[4], lsum[4];
#pragma unroll
    for (int j = 0; j < 4; ++j) { m[j] = -INFINITY; lsum[j] = 0.f; }
    f32x4 accO[8] = {};
    for (int kt = 0; kt < 32; ++kt) {
        int kvb = kt * 64;
        if (kvb >= q0 + 16) {
            // past causal frontier for this wave: continue only for degenerate rows
            bool deg = (m[0] == MINF) | (m[1] == MINF) | (m[2] == MINF) | (m[3] == MINF);
            if (!__any(deg)) break;
        }
        f32x4 sc[4] = {};
#pragma unroll
        for (int ni = 0; ni < 4; ++ni) {
            const u16* kr = &kbase[(size_t)(kvb + ni * 16 + l16) * 128 + lhi * 8];
#pragma unroll
            for (int kc = 0; kc < 4; ++kc) {
                f16x8 kf = *(const f16x8*)&kr[kc * 32];
                sc[ni] = __builtin_amdgcn_mfma_f32_16x16x32_f16(qf[kc], kf, sc[ni], 0, 0, 0);
            }
        }
        float rmax[4] = {-INFINITY, -INFINITY, -INFINITY, -INFINITY};
#pragma unroll
        for (int ni = 0; ni < 4; ++ni) {
            int key = kvb + ni * 16 + l16;
            float mk = mvb[key];
#pragma unroll
            for (int j = 0; j < 4; ++j) {
                int qrow = q0 + lhi * 4 + j;
                // exact reference arithmetic: mask = dynmask + causalMIN (f32, may overflow to -inf),
                // then score = qk*scale + mask (MIN absorbs qk*scale).
                float sval = sc[ni][j] * SCALE + (mk + (key > qrow ? MINF : 0.f));
                sc[ni][j] = sval;
                rmax[j] = fmaxf(rmax[j], sval);
            }
        }
#pragma unroll
        for (int j = 0; j < 4; ++j) {
#pragma unroll
            for (int off = 1; off < 16; off <<= 1) rmax[j] = fmaxf(rmax[j], __shfl_xor(rmax[j], off));
        }
        float r[4], psum[4];
#pragma unroll
        for (int j = 0; j < 4; ++j) {
            float mn = fmaxf(m[j], rmax[j]);
            r[j] = expf(m[j] - mn);
            m[j] = mn;
            psum[j] = 0.f;
        }
#pragma unroll
        for (int ni = 0; ni < 4; ++ni) {
#pragma unroll
            for (int j = 0; j < 4; ++j) {
                float p = expf(sc[ni][j] - m[j]);
                psum[j] += p;
                pw[(lhi * 4 + j) * 64 + ni * 16 + l16] = f2h(p);
            }
        }
#pragma unroll
        for (int j = 0; j < 4; ++j) {
#pragma unroll
            for (int off = 1; off < 16; off <<= 1) psum[j] += __shfl_xor(psum[j], off);
            lsum[j] = lsum[j] * r[j] + psum[j];
        }
#pragma unroll
        for (int db = 0; db < 8; ++db) {
#pragma unroll
            for (int j = 0; j < 4; ++j) accO[db][j] *= r[j];
        }
#pragma unroll
        for (int kc2 = 0; kc2 < 2; ++kc2) {
            f16x8 pa = *(const f16x8*)&pw[l16 * 64 + kc2 * 32 + lhi * 8];
#pragma unroll
            for (int db = 0; db < 8; ++db) {
                f16x8 vf = *(const f16x8*)&vtbase[(size_t)(db * 16 + l16) * 2048 + kvb + kc2 * 32 + lhi * 8];
                accO[db] = __builtin_amdgcn_mfma_f32_16x16x32_f16(pa, vf, accO[db], 0, 0, 0);
            }
        }
    }
#pragma unroll
    for (int db = 0; db < 8; ++db) {
#pragma unroll
        for (int j = 0; j < 4; ++j) {
            int qrow = q0 + lhi * 4 + j;
            int d = db * 16 + l16;
            float o = accO[db][j] / lsum[j];
            ao[((size_t)(b * 2048) + qrow) * 2048 + h * 128 + d] = f2h(o);
        }
    }
}

extern "C" void kernel_launch(void* const* d_in, const int* in_sizes, int n_in,
                              void* d_out, int out_size, void* d_ws, size_t ws_size,
                              hipStream_t stream) {
    const float* x = (const float*)d_in[0];
    const float* cosv = (const float*)d_in[1];
    const float* sinv = (const float*)d_in[2];
    // d_in[3] = attention_mask (deterministic causal MIN mask) -- synthesized in-kernel
    const float* Wq = (const float*)d_in[4];
    const float* Wk = (const float*)d_in[5];
    const float* Wv = (const float*)d_in[6];
    const float* Av = (const float*)d_in[7];
    const float* Wdt = (const float*)d_in[8];
    const float* Wo = (const float*)d_in[9];

    char* ws = (char*)d_ws;
    u16* qb = (u16*)(ws);                    // 16,777,216 B  (B,16,S,128) f16
    u16* kb = (u16*)(ws + 16777216);         //  8,388,608 B  (B,8,S,128) f16
    u16* vtb = (u16*)(ws + 25165824);        //  8,388,608 B  (B,8,128,S) f16
    float* dyn = (float*)(ws + 33554432);    //    262,144 B  (B,16,S) f32
    float* mval = (float*)(ws + 33816576);   //    262,144 B  (B,16,S) f32
    float* wdtv = (float*)(ws + 34078720);   //    131,072 B  (16,2048) f32
    u16* xbf = (u16*)(ws + 34209792);        // 16,777,216 B  x_f16, later attn_out
    u16* wbf = (u16*)(ws + 50987008);        // 16,777,216 B  Wqkv_f16, later Wo_f16

    // 1. conversions to f16 (8 elem/thread)
    convk8<<<8388608 / 2048, 256, 0, stream>>>(x, xbf, 8388608);
    convk8<<<4194304 / 2048, 256, 0, stream>>>(Wq, wbf, 4194304);
    convk8<<<2097152 / 2048, 256, 0, stream>>>(Wk, wbf + 4194304, 2097152);
    convk8<<<2097152 / 2048, 256, 0, stream>>>(Wv, wbf + 6291456, 2097152);

    // 2. fused QKV GEMM, scatter epilogue (q/k per-head layout, v transposed)
    dim3 g1(32, 32);
    gemm_bt<1><<<g1, 256, 0, stream>>>(xbf, wbf, nullptr, qb, kb, vtb, 4096, 2048);

    // 3. RoPE in-place on q and k
    rope_kernel<<<16384, 256, 0, stream>>>(qb, cosv, sinv, 16);
    rope_kernel<<<8192, 256, 0, stream>>>(kb, cosv, sinv, 8);

    // 4. dynamic mask: Wdtv = Wdt@Wv (f32), dt = x@Wdtv^T (f32, matches ref to ~1e-5), top-k
    wdtv_kernel<<<32, 64, 0, stream>>>(Wdt, Wv, wdtv);
    dt_dyn_kernel<<<4096, 256, 0, stream>>>(x, wdtv, Av, dyn);
    kth_mask_kernel<<<32, 1024, 0, stream>>>(dyn, mval);

    // 5. Wo -> f16 (reuses wbf; QKV GEMM is done by stream order)
    convk8<<<4194304 / 2048, 256, 0, stream>>>(Wo, wbf, 4194304);

    // 6. attention (writes attn_out into xbf)
    dim3 g2(32, 64);
    attn_kernel<<<g2, 128, 0, stream>>>(qb, kb, vtb, mval, xbf);

    // 7. output projection -> f32 d_out
    dim3 g3(16, 32);
    gemm_bt<0><<<g3, 256, 0, stream>>>(xbf, wbf, (float*)d_out, nullptr, nullptr, nullptr, 2048, 2048);
}